// Round 1
// baseline (145.185 us; speedup 1.0000x reference)
//
#include <hip/hip_runtime.h>
#include <hip/hip_bf16.h>
#include <cstddef>

// Problem constants (EmbeddingEngine_47029891891415)
#define S_ 4
#define N_ 65536
#define K_ 64
#define D_ 256
#define P_ 8192

typedef __bf16 bf16x8 __attribute__((ext_vector_type(8)));
typedef float  f32x4  __attribute__((ext_vector_type(4)));

// Pack W [S][K=64][D=256] fp32 -> bf16 MFMA B-fragments in ws.
// Layout: wpack[(((s*2 + t)*16 + c)*64 + lane)*8 + i] = bf16(W[s][t*32 + 8*(lane>>4) + i][c*16 + (lane&15)])
// Total 4*2*16*64*8 = 65536 bf16 = 128 KB.
__global__ __launch_bounds__(256) void pack_w_kernel(const float* __restrict__ W,
                                                     __bf16* __restrict__ wpack) {
    int tid  = blockIdx.x * 256 + threadIdx.x;   // 0..65535
    int i    =  tid        & 7;
    int lane = (tid >> 3)  & 63;
    int c    = (tid >> 9)  & 15;
    int t    = (tid >> 13) & 1;
    int s    =  tid >> 14;
    int k    = t * 32 + 8 * (lane >> 4) + i;
    int col  = c * 16 + (lane & 15);
    wpack[tid] = (__bf16)W[(s * K_ + k) * D_ + col];
}

// One block = one stream s, one 64-row token tile. 4 waves; wave w owns rows
// [tile*64 + w*16, +16) x all 256 cols -> 16 C-fragments of 16x16.
__global__ __launch_bounds__(256) void embed_kernel(
        const float* __restrict__ tokens,    // [S][N][K] f32
        const float* __restrict__ bvec,      // [S][D] f32
        const float* __restrict__ pe,        // [P][D] f32
        const int*   __restrict__ idxs,      // [S][N] i32
        const int*   __restrict__ idxs_pe,   // [S][N] i32
        const __bf16* __restrict__ wpack,    // packed B fragments
        float* __restrict__ out) {           // [S*N][D] f32
    const int blk   = blockIdx.x;            // 0..4095
    const int s     = blk >> 10;             // N_/64 = 1024 tiles per stream
    const int tile  = blk & 1023;
    const int wave  = threadIdx.x >> 6;
    const int lane  = threadIdx.x & 63;
    const int row16 = lane & 15;
    const int g     = lane >> 4;
    const int rowbase = tile * 64 + wave * 16;   // row within stream
    const int arow    = rowbase + row16;

    // ---- A fragments: tokens[s][arow][k], k = t*32 + 8g + i (fp32 -> bf16)
    const float* trow = tokens + ((size_t)s * N_ + arow) * K_;
    float4 a0lo = *(const float4*)(trow +      8 * g);
    float4 a0hi = *(const float4*)(trow +      8 * g + 4);
    float4 a1lo = *(const float4*)(trow + 32 + 8 * g);
    float4 a1hi = *(const float4*)(trow + 32 + 8 * g + 4);
    bf16x8 a0, a1;
    a0[0] = (__bf16)a0lo.x; a0[1] = (__bf16)a0lo.y; a0[2] = (__bf16)a0lo.z; a0[3] = (__bf16)a0lo.w;
    a0[4] = (__bf16)a0hi.x; a0[5] = (__bf16)a0hi.y; a0[6] = (__bf16)a0hi.z; a0[7] = (__bf16)a0hi.w;
    a1[0] = (__bf16)a1lo.x; a1[1] = (__bf16)a1lo.y; a1[2] = (__bf16)a1lo.z; a1[3] = (__bf16)a1lo.w;
    a1[4] = (__bf16)a1hi.x; a1[5] = (__bf16)a1hi.y; a1[6] = (__bf16)a1hi.z; a1[7] = (__bf16)a1hi.w;

    // ---- B fragments (L2-resident) + MFMA
    const bf16x8* wp0 = (const bf16x8*)wpack + (size_t)((s * 2 + 0) * 16) * 64;
    const bf16x8* wp1 = (const bf16x8*)wpack + (size_t)((s * 2 + 1) * 16) * 64;

    f32x4 acc[16];
#pragma unroll
    for (int c = 0; c < 16; ++c) acc[c] = (f32x4){0.f, 0.f, 0.f, 0.f};
#pragma unroll
    for (int c = 0; c < 16; ++c) {
        bf16x8 b0 = wp0[c * 64 + lane];
        bf16x8 b1 = wp1[c * 64 + lane];
        acc[c] = __builtin_amdgcn_mfma_f32_16x16x32_bf16(a0, b0, acc[c], 0, 0, 0);
        acc[c] = __builtin_amdgcn_mfma_f32_16x16x32_bf16(a1, b1, acc[c], 0, 0, 0);
    }

    // ---- Epilogue: C/D layout col = lane&15, row = (lane>>4)*4 + reg  [m89/m91]
    const int r0 = rowbase + g * 4;
    int orow[4], ipe[4];
#pragma unroll
    for (int r = 0; r < 4; ++r) {
        orow[r] = idxs   [s * N_ + r0 + r];
        ipe[r]  = idxs_pe[s * N_ + r0 + r];
    }
#pragma unroll
    for (int c = 0; c < 16; ++c) {
        const int col = c * 16 + row16;
        const float bb = bvec[s * D_ + col];
#pragma unroll
        for (int r = 0; r < 4; ++r) {
            float v = acc[c][r] + bb + pe[(size_t)ipe[r] * D_ + col];
            out[(size_t)orow[r] * D_ + col] = v;
        }
    }
}

extern "C" void kernel_launch(void* const* d_in, const int* in_sizes, int n_in,
                              void* d_out, int out_size, void* d_ws, size_t ws_size,
                              hipStream_t stream) {
    const float* tokens  = (const float*)d_in[0];
    const float* W       = (const float*)d_in[1];
    const float* bvec    = (const float*)d_in[2];
    const float* pe      = (const float*)d_in[3];
    const int*   idxs    = (const int*)d_in[4];
    const int*   idxs_pe = (const int*)d_in[5];
    float* out = (float*)d_out;
    __bf16* wpack = (__bf16*)d_ws;   // 128 KB

    pack_w_kernel<<<256, 256, 0, stream>>>(W, wpack);
    embed_kernel<<<S_ * (N_ / 64), 256, 0, stream>>>(tokens, bvec, pe, idxs, idxs_pe, wpack, out);
}

// Round 3
// 118.209 us; speedup vs baseline: 1.2282x; 1.2282x over previous
//
#include <hip/hip_runtime.h>
#include <hip/hip_bf16.h>
#include <cstddef>

// Problem constants (EmbeddingEngine_47029891891415)
#define S_ 4
#define N_ 65536
#define K_ 64
#define D_ 256
#define P_ 8192

typedef __bf16 bf16x8 __attribute__((ext_vector_type(8)));
typedef float  f32x4  __attribute__((ext_vector_type(4)));

// Pack W [S][K=64][D=256] fp32 -> bf16 MFMA fragments in ws.
// wpack[(((s*2 + t)*16 + c)*64 + lane)*8 + i] =
//     bf16(W[s][t*32 + 8*(lane>>4) + i][c*16 + (lane&15)])
// Used as the A-operand (A[i=d_local][k]) of mfma_f32_16x16x32_bf16:
// A-fragment mapping lane -> (i = lane&15, k = 8*(lane>>4)+e) is identical
// to the B-fragment mapping, so the same pack serves the swapped-operand GEMM.
__global__ __launch_bounds__(256) void pack_w_kernel(const float* __restrict__ W,
                                                     __bf16* __restrict__ wpack) {
    int tid  = blockIdx.x * 256 + threadIdx.x;   // 0..65535
    int i    =  tid        & 7;
    int lane = (tid >> 3)  & 63;
    int c    = (tid >> 9)  & 15;
    int t    = (tid >> 13) & 1;
    int s    =  tid >> 14;
    int k    = t * 32 + 8 * (lane >> 4) + i;
    int col  = c * 16 + (lane & 15);
    wpack[tid] = (__bf16)W[(s * K_ + k) * D_ + col];
}

// One block = one stream s, one 64-token tile. 4 waves; wave w owns tokens
// [tile*64 + w*16, +16) x all 256 D-cols.
// Swapped-operand MFMA: D[i=d_local][j=token_local] = sum_k W[k][d] * tok[j][k]
// C/D layout (m89/m91): col(lane&15) = token j, row(g*4+reg) = d_local
// -> each lane owns 4 CONSECUTIVE d elements of one token => float4 epilogue.
__global__ __launch_bounds__(256) void embed_kernel(
        const float* __restrict__ tokens,    // [S][N][K] f32
        const float* __restrict__ bvec,      // [S][D] f32
        const float* __restrict__ pe,        // [P][D] f32
        const int*   __restrict__ idxs,      // [S][N] i32
        const int*   __restrict__ idxs_pe,   // [S][N] i32
        const __bf16* __restrict__ wpack,    // packed W fragments
        float* __restrict__ out) {           // [S*N][D] f32
    const int blk   = blockIdx.x;            // 0..4095
    const int s     = blk >> 10;             // N_/64 = 1024 tiles per stream
    const int tile  = blk & 1023;
    const int wave  = threadIdx.x >> 6;
    const int lane  = threadIdx.x & 63;
    const int j     = lane & 15;             // token within wave tile
    const int g     = lane >> 4;
    const int rowbase = tile * 64 + wave * 16;
    const int trowi   = rowbase + j;         // token row within stream

    // ---- token B-fragments: tok[trowi][k], k = t*32 + 8g + e (fp32 -> bf16, streaming)
    const float* trow = tokens + ((size_t)s * N_ + trowi) * K_;
    f32x4 t0lo = __builtin_nontemporal_load((const f32x4*)(trow +      8 * g));
    f32x4 t0hi = __builtin_nontemporal_load((const f32x4*)(trow +      8 * g + 4));
    f32x4 t1lo = __builtin_nontemporal_load((const f32x4*)(trow + 32 + 8 * g));
    f32x4 t1hi = __builtin_nontemporal_load((const f32x4*)(trow + 32 + 8 * g + 4));
    bf16x8 a0, a1;
#pragma unroll
    for (int e = 0; e < 4; ++e) {
        a0[e]     = (__bf16)t0lo[e];
        a0[e + 4] = (__bf16)t0hi[e];
        a1[e]     = (__bf16)t1lo[e];
        a1[e + 4] = (__bf16)t1hi[e];
    }

    // ---- W A-fragments (L2-resident) + MFMA (swapped operands)
    const bf16x8* wp0 = (const bf16x8*)wpack + (size_t)((s * 2 + 0) * 16) * 64;
    const bf16x8* wp1 = (const bf16x8*)wpack + (size_t)((s * 2 + 1) * 16) * 64;

    f32x4 acc[16];
#pragma unroll
    for (int c = 0; c < 16; ++c) acc[c] = (f32x4){0.f, 0.f, 0.f, 0.f};
#pragma unroll
    for (int c = 0; c < 16; ++c) {
        bf16x8 w0 = wp0[c * 64 + lane];
        bf16x8 w1 = wp1[c * 64 + lane];
        acc[c] = __builtin_amdgcn_mfma_f32_16x16x32_bf16(w0, a0, acc[c], 0, 0, 0);
        acc[c] = __builtin_amdgcn_mfma_f32_16x16x32_bf16(w1, a1, acc[c], 0, 0, 0);
    }

    // ---- Epilogue: lane owns token trowi, d = c*16 + g*4 + {0..3}
    const int orow = idxs   [s * N_ + trowi];
    const int ipe  = idxs_pe[s * N_ + trowi];
    const float* __restrict__ perow = pe + (size_t)ipe * D_;
    const float* __restrict__ brow  = bvec + s * D_;
    float* __restrict__ optr        = out + (size_t)orow * D_;
#pragma unroll
    for (int c = 0; c < 16; ++c) {
        const int d0 = c * 16 + g * 4;
        f32x4 pev = *(const f32x4*)(perow + d0);
        f32x4 bbv = *(const f32x4*)(brow  + d0);
        f32x4 o   = acc[c] + bbv + pev;
        __builtin_nontemporal_store(o, (f32x4*)(optr + d0));
    }
}

extern "C" void kernel_launch(void* const* d_in, const int* in_sizes, int n_in,
                              void* d_out, int out_size, void* d_ws, size_t ws_size,
                              hipStream_t stream) {
    const float* tokens  = (const float*)d_in[0];
    const float* W       = (const float*)d_in[1];
    const float* bvec    = (const float*)d_in[2];
    const float* pe      = (const float*)d_in[3];
    const int*   idxs    = (const int*)d_in[4];
    const int*   idxs_pe = (const int*)d_in[5];
    float* out = (float*)d_out;
    __bf16* wpack = (__bf16*)d_ws;   // 128 KB

    pack_w_kernel<<<256, 256, 0, stream>>>(W, wpack);
    embed_kernel<<<S_ * (N_ / 64), 256, 0, stream>>>(tokens, bvec, pe, idxs, idxs_pe, wpack, out);
}